// Round 5
// baseline (342.566 us; speedup 1.0000x reference)
//
#include <hip/hip_runtime.h>
#include <hip/hip_bf16.h>
#include <cstdint>

typedef __attribute__((ext_vector_type(8))) __bf16 bf16x8;
typedef __attribute__((ext_vector_type(4))) __bf16 bf16x4;
typedef __attribute__((ext_vector_type(4))) float f32x4;

#define MFMA16(a, b, c) __builtin_amdgcn_mfma_f32_16x16x32_bf16(a, b, c, 0, 0, 0)

static constexpr float SCQ = 0.18033688f;  // (1/sqrt(64)) * log2(e)

__device__ __forceinline__ void gload16(const void* g, void* l) {
  __builtin_amdgcn_global_load_lds(
      (const __attribute__((address_space(1))) void*)g,
      (__attribute__((address_space(3))) void*)l, 16, 0, 0);
}

// ---------------------------------------------------------------------------
// conv_x: f32 [8192][1024] -> bf16 same layout
// ---------------------------------------------------------------------------
__global__ __launch_bounds__(256) void conv_x(const float* __restrict__ in,
                                              __bf16* __restrict__ out) {
  const size_t i = ((size_t)blockIdx.x * 256 + threadIdx.x) * 8;
  const float4 v0 = *(const float4*)(in + i);
  const float4 v1 = *(const float4*)(in + i + 4);
  bf16x8 o = {(__bf16)v0.x, (__bf16)v0.y, (__bf16)v0.z, (__bf16)v0.w,
              (__bf16)v1.x, (__bf16)v1.y, (__bf16)v1.z, (__bf16)v1.w};
  *(bf16x8*)(out + i) = o;
}

// ---------------------------------------------------------------------------
// conv_wt: W f32 [K][N] -> Wt bf16 [N][K]  (transpose via LDS tile)
// ---------------------------------------------------------------------------
__global__ __launch_bounds__(256) void conv_wt(const float* __restrict__ W,
                                               __bf16* __restrict__ Wt,
                                               int K, int N) {
  __shared__ float tile[64][65];
  const int nb = blockIdx.x * 64, kb = blockIdx.y * 64;
  const int t = threadIdx.x, tr = t >> 4, tc = t & 15;
  #pragma unroll
  for (int p = 0; p < 4; ++p) {
    const float4 v =
        *(const float4*)(W + (size_t)(kb + p * 16 + tr) * N + nb + tc * 4);
    tile[p * 16 + tr][tc * 4 + 0] = v.x;
    tile[p * 16 + tr][tc * 4 + 1] = v.y;
    tile[p * 16 + tr][tc * 4 + 2] = v.z;
    tile[p * 16 + tr][tc * 4 + 3] = v.w;
  }
  __syncthreads();
  #pragma unroll
  for (int p = 0; p < 4; ++p) {
    const int n = p * 16 + tr, kk = tc * 4;
    bf16x4 o = {(__bf16)tile[kk + 0][n], (__bf16)tile[kk + 1][n],
                (__bf16)tile[kk + 2][n], (__bf16)tile[kk + 3][n]};
    *(bf16x4*)(Wt + (size_t)(nb + n) * K + kb + kk) = o;
  }
}

// ---------------------------------------------------------------------------
// GEMM core (m97 structure): 128x128 tile, BK=32, global_load_lds w=16,
// linear LDS.  A bf16 [M][1024] row-major, Bt bf16 [N][1024] row-major (B^T).
// V is stored sigma-permuted within each 32-column block of the sequence dim
// so attention can load PV B-fragment-ordered V with single b128 loads:
//   sigma(v) = 8*((v>>2)&3) + 4*(v>>4) + (v&3),  v = s & 31.
// ---------------------------------------------------------------------------
__global__ __launch_bounds__(256) void qkv_gemm_b(
    const __bf16* __restrict__ A, const __bf16* __restrict__ Bt,
    const float* __restrict__ bias,
    __bf16* __restrict__ Qb, __bf16* __restrict__ Kb, __bf16* __restrict__ Vt)
{
  __shared__ alignas(16) __bf16 a_sh[128 * 32];
  __shared__ alignas(16) __bf16 b_sh[128 * 32];
  const int n0 = blockIdx.x * 128, m0 = blockIdx.y * 128;
  const int t = threadIdx.x, wave = t >> 6, lane = t & 63;
  const int r = lane & 15, g = lane >> 4;
  const int wm = (wave >> 1) * 64, wn = (wave & 1) * 64;
  f32x4 acc[4][4] = {};

  const int srow = wave * 16 + (lane >> 2);
  const int scol = (lane & 3) * 8;
  const __bf16* gA = A + (size_t)(m0 + srow) * 1024 + scol;
  const __bf16* gB = Bt + (size_t)(n0 + srow) * 1024 + scol;
  __bf16* lA = a_sh + wave * 512;
  __bf16* lB = b_sh + wave * 512;

  for (int k0 = 0; k0 < 1024; k0 += 32) {
    __syncthreads();
    gload16(gA + k0, lA);
    gload16(gA + 64 * 1024 + k0, lA + 2048);
    gload16(gB + k0, lB);
    gload16(gB + 64 * 1024 + k0, lB + 2048);
    __syncthreads();
    bf16x8 af[4], bfr[4];
    #pragma unroll
    for (int i = 0; i < 4; ++i)
      af[i] = *(bf16x8*)&a_sh[(wm + i * 16 + r) * 32 + g * 8];
    #pragma unroll
    for (int j = 0; j < 4; ++j)
      bfr[j] = *(bf16x8*)&b_sh[(wn + j * 16 + r) * 32 + g * 8];
    #pragma unroll
    for (int i = 0; i < 4; ++i)
      #pragma unroll
      for (int j = 0; j < 4; ++j)
        acc[i][j] = MFMA16(af[i], bfr[j], acc[i][j]);
  }

  const int which = n0 >> 10;  // 0=Q 1=K 2=V
  const int bb = m0 >> 11;
  const int sbase = (m0 & 2047) + wm;
  #pragma unroll
  for (int j = 0; j < 4; ++j) {
    const int nc = n0 + wn + j * 16 + r;
    const float bv = bias[nc];
    const int hh = (nc & 1023) >> 6;
    const int d = nc & 63;
    #pragma unroll
    for (int i = 0; i < 4; ++i) {
      const int ss0 = sbase + i * 16 + g * 4;
      if (which == 0) {
        #pragma unroll
        for (int rr = 0; rr < 4; ++rr)
          Qb[((size_t)(bb * 16 + hh) * 2048 + ss0 + rr) * 64 + d] =
              (__bf16)((acc[i][j][rr] + bv) * SCQ);
      } else if (which == 1) {
        #pragma unroll
        for (int rr = 0; rr < 4; ++rr)
          Kb[((size_t)(bb * 16 + hh) * 2048 + ss0 + rr) * 64 + d] =
              (__bf16)(acc[i][j][rr] + bv);
      } else {
        bf16x4 vv;
        #pragma unroll
        for (int rr = 0; rr < 4; ++rr) vv[rr] = (__bf16)(acc[i][j][rr] + bv);
        const int v5 = ss0 & 31;  // multiple of 4
        const int pcol = (ss0 & ~31) + 8 * ((v5 >> 2) & 3) + 4 * (v5 >> 4);
        *(bf16x4*)&Vt[((size_t)(bb * 16 + hh) * 64 + d) * 2048 + pcol] = vv;
      }
    }
  }
}

__global__ __launch_bounds__(256) void proj_gemm_b(
    const __bf16* __restrict__ A, const __bf16* __restrict__ Bt,
    const float* __restrict__ bias, float* __restrict__ out)
{
  __shared__ alignas(16) __bf16 a_sh[128 * 32];
  __shared__ alignas(16) __bf16 b_sh[128 * 32];
  const int n0 = blockIdx.x * 128, m0 = blockIdx.y * 128;
  const int t = threadIdx.x, wave = t >> 6, lane = t & 63;
  const int r = lane & 15, g = lane >> 4;
  const int wm = (wave >> 1) * 64, wn = (wave & 1) * 64;
  f32x4 acc[4][4] = {};

  const int srow = wave * 16 + (lane >> 2);
  const int scol = (lane & 3) * 8;
  const __bf16* gA = A + (size_t)(m0 + srow) * 1024 + scol;
  const __bf16* gB = Bt + (size_t)(n0 + srow) * 1024 + scol;
  __bf16* lA = a_sh + wave * 512;
  __bf16* lB = b_sh + wave * 512;

  for (int k0 = 0; k0 < 1024; k0 += 32) {
    __syncthreads();
    gload16(gA + k0, lA);
    gload16(gA + 64 * 1024 + k0, lA + 2048);
    gload16(gB + k0, lB);
    gload16(gB + 64 * 1024 + k0, lB + 2048);
    __syncthreads();
    bf16x8 af[4], bfr[4];
    #pragma unroll
    for (int i = 0; i < 4; ++i)
      af[i] = *(bf16x8*)&a_sh[(wm + i * 16 + r) * 32 + g * 8];
    #pragma unroll
    for (int j = 0; j < 4; ++j)
      bfr[j] = *(bf16x8*)&b_sh[(wn + j * 16 + r) * 32 + g * 8];
    #pragma unroll
    for (int i = 0; i < 4; ++i)
      #pragma unroll
      for (int j = 0; j < 4; ++j)
        acc[i][j] = MFMA16(af[i], bfr[j], acc[i][j]);
  }

  #pragma unroll
  for (int j = 0; j < 4; ++j) {
    const int nc = n0 + wn + j * 16 + r;
    const float bv = bias[nc];
    #pragma unroll
    for (int i = 0; i < 4; ++i)
      #pragma unroll
      for (int rr = 0; rr < 4; ++rr)
        out[(size_t)(m0 + wm + i * 16 + g * 4 + rr) * 1024 + nc] =
            acc[i][j][rr] + bv;
  }
}

// ---------------------------------------------------------------------------
// Flash attention v4: LDS-free, barrier-free.  4 waves x 32 q = 128 q/block,
// 1024 blocks; each wave fully independent.  K and (sigma-permuted) V read
// directly from global (L2-resident per XCD via block swizzle).  Swapped
// QK^T with seeded-C, defer-max, lane-local P.
// ---------------------------------------------------------------------------
__global__ __launch_bounds__(256, 3) void attn_kernel(
    const __bf16* __restrict__ Q, const __bf16* __restrict__ K,
    const __bf16* __restrict__ Vt, __bf16* __restrict__ AO)
{
  const int p = blockIdx.x;
  const int hd = (p & 7) + 8 * (p >> 7);   // head linear = b*16+h, per-XCD
  const int qt = (p >> 3) & 15;
  const int b = hd >> 4, h = hd & 15;

  const int t = threadIdx.x, wave = t >> 6, lane = t & 63;
  const int r = lane & 15, g = lane >> 4;

  const __bf16* Qp = Q + (size_t)hd * (2048 * 64);
  const __bf16* gK = K + (size_t)hd * (2048 * 64) + (size_t)r * 64 + g * 8;
  const __bf16* gV = Vt + (size_t)hd * (64 * 2048) + (size_t)r * 2048 + g * 8;
  const int q0 = qt * 128 + wave * 32;

  // Q fragments (pre-scaled by SCQ at QKV epilogue)
  bf16x8 qf[2][2];
  #pragma unroll
  for (int qh = 0; qh < 2; ++qh)
    #pragma unroll
    for (int hh = 0; hh < 2; ++hh)
      qf[qh][hh] =
          *(const bf16x8*)(Qp + (size_t)(q0 + qh * 16 + r) * 64 + hh * 32 + g * 8);

  float mrun[2] = {0.f, 0.f};
  float lrun[2] = {0.f, 0.f};
  f32x4 o[4][2] = {};

  for (int k0 = 0; k0 < 2048; k0 += 64) {
    // --- K fragment loads (L2) ---
    bf16x8 kf0[4], kf1[4];
    #pragma unroll
    for (int kt = 0; kt < 4; ++kt) {
      kf0[kt] = *(const bf16x8*)(gK + (size_t)(k0 + kt * 16) * 64);
      kf1[kt] = *(const bf16x8*)(gK + (size_t)(k0 + kt * 16) * 64 + 32);
    }

    // --- QK^T (swapped), C seeded with -m ---
    f32x4 sacc[4][2];
    const f32x4 seed0 = {-mrun[0], -mrun[0], -mrun[0], -mrun[0]};
    const f32x4 seed1 = {-mrun[1], -mrun[1], -mrun[1], -mrun[1]};
    __builtin_amdgcn_s_setprio(1);
    #pragma unroll
    for (int kt = 0; kt < 4; ++kt) {
      f32x4 s0 = MFMA16(kf0[kt], qf[0][0], seed0);
      s0 = MFMA16(kf1[kt], qf[0][1], s0);
      sacc[kt][0] = s0;
      f32x4 s1 = MFMA16(kf0[kt], qf[1][0], seed1);
      s1 = MFMA16(kf1[kt], qf[1][1], s1);
      sacc[kt][1] = s1;
    }
    __builtin_amdgcn_s_setprio(0);

    // --- V fragment loads (issued now; latency hides under softmax) ---
    bf16x8 vf[2][4];
    #pragma unroll
    for (int c = 0; c < 2; ++c)
      #pragma unroll
      for (int dt = 0; dt < 4; ++dt)
        vf[c][dt] =
            *(const bf16x8*)(gV + (size_t)(dt * 16) * 2048 + k0 + c * 32);

    // --- online softmax with defer-max; P packed lane-local ---
    bf16x8 pf[2][2];
    #pragma unroll
    for (int qh = 0; qh < 2; ++qh) {
      // max over 16 values (max3-friendly nesting) + 2 shfl
      float a0 = fmaxf(fmaxf(sacc[0][qh][0], sacc[0][qh][1]),
                       fmaxf(sacc[0][qh][2], sacc[0][qh][3]));
      float a1 = fmaxf(fmaxf(sacc[1][qh][0], sacc[1][qh][1]),
                       fmaxf(sacc[1][qh][2], sacc[1][qh][3]));
      float a2 = fmaxf(fmaxf(sacc[2][qh][0], sacc[2][qh][1]),
                       fmaxf(sacc[2][qh][2], sacc[2][qh][3]));
      float a3 = fmaxf(fmaxf(sacc[3][qh][0], sacc[3][qh][1]),
                       fmaxf(sacc[3][qh][2], sacc[3][qh][3]));
      float tm = fmaxf(fmaxf(a0, a1), fmaxf(a2, a3));
      tm = fmaxf(tm, __shfl_xor(tm, 16));
      tm = fmaxf(tm, __shfl_xor(tm, 32));

      float pv[4][4];
      float ps = 0.f;
      if (__any(tm > 6.0f)) {
        const float dl = fmaxf(tm, 0.f);
        const float al = exp2f(-dl);
        mrun[qh] += dl;
        #pragma unroll
        for (int kt = 0; kt < 4; ++kt)
          #pragma unroll
          for (int rr = 0; rr < 4; ++rr) {
            const float pp = exp2f(sacc[kt][qh][rr] - dl);
            pv[kt][rr] = pp;
            ps += pp;
          }
        ps += __shfl_xor(ps, 16);
        ps += __shfl_xor(ps, 32);
        lrun[qh] = lrun[qh] * al + ps;
        #pragma unroll
        for (int dt = 0; dt < 4; ++dt)
          #pragma unroll
          for (int rr = 0; rr < 4; ++rr)
            o[dt][qh][rr] *= al;
      } else {
        #pragma unroll
        for (int kt = 0; kt < 4; ++kt)
          #pragma unroll
          for (int rr = 0; rr < 4; ++rr) {
            const float pp = exp2f(sacc[kt][qh][rr]);
            pv[kt][rr] = pp;
            ps += pp;
          }
        ps += __shfl_xor(ps, 16);
        ps += __shfl_xor(ps, 32);
        lrun[qh] += ps;
      }
      // pf[c][j] = P at key 32c + 16*(j>>2) + 4g + (j&3)  (adjacent pairs
      // are pv[x][0..3] -> cvt_pk-friendly)
      #pragma unroll
      for (int c = 0; c < 2; ++c)
        #pragma unroll
        for (int j = 0; j < 8; ++j)
          pf[qh][c][j] = (__bf16)pv[2 * c + (j >> 2)][j & 3];
    }

    // --- PV: A = V (sigma-ordered), B = P (same order) ---
    __builtin_amdgcn_s_setprio(1);
    #pragma unroll
    for (int c = 0; c < 2; ++c)
      #pragma unroll
      for (int dt = 0; dt < 4; ++dt) {
        o[dt][0] = MFMA16(vf[c][dt], pf[0][c], o[dt][0]);
        o[dt][1] = MFMA16(vf[c][dt], pf[1][c], o[dt][1]);
      }
    __builtin_amdgcn_s_setprio(0);
  }

  // --- epilogue: normalize, write AO[b, s, h*64+d] (d = dt*16+4g+rr) ---
  #pragma unroll
  for (int qh = 0; qh < 2; ++qh) {
    const float inv = 1.0f / lrun[qh];
    const int ss = q0 + qh * 16 + r;
    #pragma unroll
    for (int dt = 0; dt < 4; ++dt) {
      bf16x4 ov;
      #pragma unroll
      for (int rr = 0; rr < 4; ++rr)
        ov[rr] = (__bf16)(o[dt][qh][rr] * inv);
      *(bf16x4*)&AO[((size_t)b * 2048 + ss) * 1024 + h * 64 + dt * 16 + 4 * g] = ov;
    }
  }
}

// ---------------------------------------------------------------------------
extern "C" void kernel_launch(void* const* d_in, const int* in_sizes, int n_in,
                              void* d_out, int out_size, void* d_ws, size_t ws_size,
                              hipStream_t stream) {
  (void)in_sizes; (void)n_in; (void)out_size; (void)ws_size;
  const float* x      = (const float*)d_in[0];
  const float* w_qkv  = (const float*)d_in[1];
  const float* b_qkv  = (const float*)d_in[2];
  const float* w_proj = (const float*)d_in[3];
  const float* b_proj = (const float*)d_in[4];
  float* out = (float*)d_out;

  char* ws = (char*)d_ws;
  const size_t E2 = (size_t)8192 * 1024 * 2;  // bytes per [8192][1024] bf16
  __bf16* Qb  = (__bf16*)(ws);
  __bf16* Kb  = (__bf16*)(ws + E2);
  __bf16* Vt  = (__bf16*)(ws + 2 * E2);
  __bf16* Xb  = (__bf16*)(ws + 3 * E2);
  __bf16* AO  = Xb;  // Xb dead after qkv_gemm_b; reuse for attention output
  __bf16* Wqt = (__bf16*)(ws + 4 * E2);
  __bf16* Wpt = (__bf16*)(ws + 4 * E2 + (size_t)3072 * 1024 * 2);

  conv_x<<<4096, 256, 0, stream>>>(x, Xb);
  conv_wt<<<dim3(48, 16), 256, 0, stream>>>(w_qkv, Wqt, 1024, 3072);
  conv_wt<<<dim3(16, 16), 256, 0, stream>>>(w_proj, Wpt, 1024, 1024);
  qkv_gemm_b<<<dim3(24, 64), 256, 0, stream>>>(Xb, Wqt, b_qkv, Qb, Kb, Vt);
  attn_kernel<<<1024, 256, 0, stream>>>(Qb, Kb, Vt, AO);
  proj_gemm_b<<<dim3(8, 64), 256, 0, stream>>>(AO, Wpt, b_proj, out);
}

// Round 6
// 243.053 us; speedup vs baseline: 1.4094x; 1.4094x over previous
//
#include <hip/hip_runtime.h>
#include <hip/hip_bf16.h>
#include <cstdint>

typedef __attribute__((ext_vector_type(8))) __bf16 bf16x8;
typedef __attribute__((ext_vector_type(4))) __bf16 bf16x4;
typedef __attribute__((ext_vector_type(4))) float f32x4;

#define MFMA16(a, b, c) __builtin_amdgcn_mfma_f32_16x16x32_bf16(a, b, c, 0, 0, 0)

static constexpr float SCQ = 0.18033688f;  // (1/sqrt(64)) * log2(e)

__device__ __forceinline__ void gload16(const void* g, void* l) {
  __builtin_amdgcn_global_load_lds(
      (const __attribute__((address_space(1))) void*)g,
      (__attribute__((address_space(3))) void*)l, 16, 0, 0);
}

// ---------------------------------------------------------------------------
// conv_x: f32 [8192][1024] -> bf16 same layout
// ---------------------------------------------------------------------------
__global__ __launch_bounds__(256) void conv_x(const float* __restrict__ in,
                                              __bf16* __restrict__ out) {
  const size_t i = ((size_t)blockIdx.x * 256 + threadIdx.x) * 8;
  const float4 v0 = *(const float4*)(in + i);
  const float4 v1 = *(const float4*)(in + i + 4);
  bf16x8 o = {(__bf16)v0.x, (__bf16)v0.y, (__bf16)v0.z, (__bf16)v0.w,
              (__bf16)v1.x, (__bf16)v1.y, (__bf16)v1.z, (__bf16)v1.w};
  *(bf16x8*)(out + i) = o;
}

// ---------------------------------------------------------------------------
// conv_wt: W f32 [K][N] -> Wt bf16 [N][K]  (transpose via LDS tile)
// ---------------------------------------------------------------------------
__global__ __launch_bounds__(256) void conv_wt(const float* __restrict__ W,
                                               __bf16* __restrict__ Wt,
                                               int K, int N) {
  __shared__ float tile[64][65];
  const int nb = blockIdx.x * 64, kb = blockIdx.y * 64;
  const int t = threadIdx.x, tr = t >> 4, tc = t & 15;
  #pragma unroll
  for (int p = 0; p < 4; ++p) {
    const float4 v =
        *(const float4*)(W + (size_t)(kb + p * 16 + tr) * N + nb + tc * 4);
    tile[p * 16 + tr][tc * 4 + 0] = v.x;
    tile[p * 16 + tr][tc * 4 + 1] = v.y;
    tile[p * 16 + tr][tc * 4 + 2] = v.z;
    tile[p * 16 + tr][tc * 4 + 3] = v.w;
  }
  __syncthreads();
  #pragma unroll
  for (int p = 0; p < 4; ++p) {
    const int n = p * 16 + tr, kk = tc * 4;
    bf16x4 o = {(__bf16)tile[kk + 0][n], (__bf16)tile[kk + 1][n],
                (__bf16)tile[kk + 2][n], (__bf16)tile[kk + 3][n]};
    *(bf16x4*)(Wt + (size_t)(nb + n) * K + kb + kk) = o;
  }
}

// ---------------------------------------------------------------------------
// GEMM core (m97 structure): 128x128 tile, BK=32, global_load_lds w=16,
// linear LDS.  A bf16 [M][1024] row-major, Bt bf16 [N][1024] row-major (B^T).
// V is stored sigma-permuted within each 32-column block of the sequence dim
// so attention's PV B-fragments are in MFMA lane order:
//   sigma: key s (w = s&31 = 4a+b) -> col (s&~31) + 8*(a&3) + 4*(a>>2) + b.
// ---------------------------------------------------------------------------
__global__ __launch_bounds__(256) void qkv_gemm_b(
    const __bf16* __restrict__ A, const __bf16* __restrict__ Bt,
    const float* __restrict__ bias,
    __bf16* __restrict__ Qb, __bf16* __restrict__ Kb, __bf16* __restrict__ Vt)
{
  __shared__ alignas(16) __bf16 a_sh[128 * 32];
  __shared__ alignas(16) __bf16 b_sh[128 * 32];
  const int n0 = blockIdx.x * 128, m0 = blockIdx.y * 128;
  const int t = threadIdx.x, wave = t >> 6, lane = t & 63;
  const int r = lane & 15, g = lane >> 4;
  const int wm = (wave >> 1) * 64, wn = (wave & 1) * 64;
  f32x4 acc[4][4] = {};

  const int srow = wave * 16 + (lane >> 2);
  const int scol = (lane & 3) * 8;
  const __bf16* gA = A + (size_t)(m0 + srow) * 1024 + scol;
  const __bf16* gB = Bt + (size_t)(n0 + srow) * 1024 + scol;
  __bf16* lA = a_sh + wave * 512;
  __bf16* lB = b_sh + wave * 512;

  for (int k0 = 0; k0 < 1024; k0 += 32) {
    __syncthreads();
    gload16(gA + k0, lA);
    gload16(gA + 64 * 1024 + k0, lA + 2048);
    gload16(gB + k0, lB);
    gload16(gB + 64 * 1024 + k0, lB + 2048);
    __syncthreads();
    bf16x8 af[4], bfr[4];
    #pragma unroll
    for (int i = 0; i < 4; ++i)
      af[i] = *(bf16x8*)&a_sh[(wm + i * 16 + r) * 32 + g * 8];
    #pragma unroll
    for (int j = 0; j < 4; ++j)
      bfr[j] = *(bf16x8*)&b_sh[(wn + j * 16 + r) * 32 + g * 8];
    #pragma unroll
    for (int i = 0; i < 4; ++i)
      #pragma unroll
      for (int j = 0; j < 4; ++j)
        acc[i][j] = MFMA16(af[i], bfr[j], acc[i][j]);
  }

  const int which = n0 >> 10;  // 0=Q 1=K 2=V
  const int bb = m0 >> 11;
  const int sbase = (m0 & 2047) + wm;
  #pragma unroll
  for (int j = 0; j < 4; ++j) {
    const int nc = n0 + wn + j * 16 + r;
    const float bv = bias[nc];
    const int hh = (nc & 1023) >> 6;
    const int d = nc & 63;
    #pragma unroll
    for (int i = 0; i < 4; ++i) {
      const int ss0 = sbase + i * 16 + g * 4;
      if (which == 0) {
        #pragma unroll
        for (int rr = 0; rr < 4; ++rr)
          Qb[((size_t)(bb * 16 + hh) * 2048 + ss0 + rr) * 64 + d] =
              (__bf16)((acc[i][j][rr] + bv) * SCQ);
      } else if (which == 1) {
        #pragma unroll
        for (int rr = 0; rr < 4; ++rr)
          Kb[((size_t)(bb * 16 + hh) * 2048 + ss0 + rr) * 64 + d] =
              (__bf16)(acc[i][j][rr] + bv);
      } else {
        bf16x4 vv;
        #pragma unroll
        for (int rr = 0; rr < 4; ++rr) vv[rr] = (__bf16)(acc[i][j][rr] + bv);
        const int v5 = ss0 & 31;  // multiple of 4
        const int pcol = (ss0 & ~31) + 8 * ((v5 >> 2) & 3) + 4 * (v5 >> 4);
        *(bf16x4*)&Vt[((size_t)(bb * 16 + hh) * 64 + d) * 2048 + pcol] = vv;
      }
    }
  }
}

__global__ __launch_bounds__(256) void proj_gemm_b(
    const __bf16* __restrict__ A, const __bf16* __restrict__ Bt,
    const float* __restrict__ bias, float* __restrict__ out)
{
  __shared__ alignas(16) __bf16 a_sh[128 * 32];
  __shared__ alignas(16) __bf16 b_sh[128 * 32];
  const int n0 = blockIdx.x * 128, m0 = blockIdx.y * 128;
  const int t = threadIdx.x, wave = t >> 6, lane = t & 63;
  const int r = lane & 15, g = lane >> 4;
  const int wm = (wave >> 1) * 64, wn = (wave & 1) * 64;
  f32x4 acc[4][4] = {};

  const int srow = wave * 16 + (lane >> 2);
  const int scol = (lane & 3) * 8;
  const __bf16* gA = A + (size_t)(m0 + srow) * 1024 + scol;
  const __bf16* gB = Bt + (size_t)(n0 + srow) * 1024 + scol;
  __bf16* lA = a_sh + wave * 512;
  __bf16* lB = b_sh + wave * 512;

  for (int k0 = 0; k0 < 1024; k0 += 32) {
    __syncthreads();
    gload16(gA + k0, lA);
    gload16(gA + 64 * 1024 + k0, lA + 2048);
    gload16(gB + k0, lB);
    gload16(gB + 64 * 1024 + k0, lB + 2048);
    __syncthreads();
    bf16x8 af[4], bfr[4];
    #pragma unroll
    for (int i = 0; i < 4; ++i)
      af[i] = *(bf16x8*)&a_sh[(wm + i * 16 + r) * 32 + g * 8];
    #pragma unroll
    for (int j = 0; j < 4; ++j)
      bfr[j] = *(bf16x8*)&b_sh[(wn + j * 16 + r) * 32 + g * 8];
    #pragma unroll
    for (int i = 0; i < 4; ++i)
      #pragma unroll
      for (int j = 0; j < 4; ++j)
        acc[i][j] = MFMA16(af[i], bfr[j], acc[i][j]);
  }

  #pragma unroll
  for (int j = 0; j < 4; ++j) {
    const int nc = n0 + wn + j * 16 + r;
    const float bv = bias[nc];
    #pragma unroll
    for (int i = 0; i < 4; ++i)
      #pragma unroll
      for (int rr = 0; rr < 4; ++rr)
        out[(size_t)(m0 + wm + i * 16 + g * 4 + rr) * 1024 + nc] =
            acc[i][j][rr] + bv;
  }
}

// ---------------------------------------------------------------------------
// Flash attention v5 = r2's proven staging structure + VALU diet.
// Block = 128 q-rows (4 waves x 32 q), 1024 blocks, XCD-swizzled.
// K/V tiles staged in pad-72 LDS (V already sigma-permuted in global ->
// linear copy).  Swapped QK^T with C seeded by -m, defer-max (THR=6),
// lane-local P, setprio around MFMA clusters.
// ---------------------------------------------------------------------------
__global__ __launch_bounds__(256, 4) void attn_kernel(
    const __bf16* __restrict__ Q, const __bf16* __restrict__ K,
    const __bf16* __restrict__ Vt, __bf16* __restrict__ AO)
{
  __shared__ alignas(16) __bf16 k_sh[64][72];
  __shared__ alignas(16) __bf16 v_sh[64][72];

  const int p = blockIdx.x;
  const int hd = (p & 7) + 8 * (p >> 7);   // head linear = b*16+h; 8 heads/XCD
  const int qt = (p >> 3) & 15;
  const int b = hd >> 4, h = hd & 15;

  const int t = threadIdx.x, wave = t >> 6, lane = t & 63;
  const int r = lane & 15, g = lane >> 4;

  const __bf16* Qp = Q + (size_t)hd * (2048 * 64);
  const __bf16* Kp = K + (size_t)hd * (2048 * 64);
  const __bf16* Vp = Vt + (size_t)hd * (64 * 2048);
  const int q0 = qt * 128 + wave * 32;

  // staging map: thread t covers row sr = t>>2, element cols sc, sc+32
  const int sr = t >> 2;
  const int sc = (t & 3) * 8;
  const __bf16* gK = Kp + (size_t)sr * 64 + sc;   // key row sr, d col sc
  const __bf16* gV = Vp + (size_t)sr * 2048 + sc; // d row sr, key col sc

  // Q fragments (pre-scaled by SCQ at QKV epilogue)
  bf16x8 qf[2][2];
  #pragma unroll
  for (int qh = 0; qh < 2; ++qh)
    #pragma unroll
    for (int hh = 0; hh < 2; ++hh)
      qf[qh][hh] =
          *(const bf16x8*)(Qp + (size_t)(q0 + qh * 16 + r) * 64 + hh * 32 + g * 8);

  float mrun[2] = {0.f, 0.f};
  float lrun[2] = {0.f, 0.f};
  f32x4 o[4][2] = {};

  for (int k0 = 0; k0 < 2048; k0 += 64) {
    __syncthreads();
    *(bf16x8*)&k_sh[sr][sc] = *(const bf16x8*)(gK + (size_t)k0 * 64);
    *(bf16x8*)&k_sh[sr][sc + 32] = *(const bf16x8*)(gK + (size_t)k0 * 64 + 32);
    *(bf16x8*)&v_sh[sr][sc] = *(const bf16x8*)(gV + k0);
    *(bf16x8*)&v_sh[sr][sc + 32] = *(const bf16x8*)(gV + k0 + 32);
    __syncthreads();

    // --- QK^T (swapped): sacc[kt][qh] = S_log2[k=16kt+4g+rr][q=r] - m ---
    f32x4 sacc[4][2];
    const f32x4 seed0 = {-mrun[0], -mrun[0], -mrun[0], -mrun[0]};
    const f32x4 seed1 = {-mrun[1], -mrun[1], -mrun[1], -mrun[1]};
    __builtin_amdgcn_s_setprio(1);
    #pragma unroll
    for (int kt = 0; kt < 4; ++kt) {
      const bf16x8 kf0 = *(const bf16x8*)&k_sh[kt * 16 + r][g * 8];
      const bf16x8 kf1 = *(const bf16x8*)&k_sh[kt * 16 + r][32 + g * 8];
      f32x4 s0 = MFMA16(kf0, qf[0][0], seed0);
      s0 = MFMA16(kf1, qf[0][1], s0);
      sacc[kt][0] = s0;
      f32x4 s1 = MFMA16(kf0, qf[1][0], seed1);
      s1 = MFMA16(kf1, qf[1][1], s1);
      sacc[kt][1] = s1;
    }
    __builtin_amdgcn_s_setprio(0);

    // --- online softmax with defer-max; P packed lane-local (pi order) ---
    bf16x8 pf[2][2];
    #pragma unroll
    for (int qh = 0; qh < 2; ++qh) {
      float a0 = fmaxf(fmaxf(sacc[0][qh][0], sacc[0][qh][1]),
                       fmaxf(sacc[0][qh][2], sacc[0][qh][3]));
      float a1 = fmaxf(fmaxf(sacc[1][qh][0], sacc[1][qh][1]),
                       fmaxf(sacc[1][qh][2], sacc[1][qh][3]));
      float a2 = fmaxf(fmaxf(sacc[2][qh][0], sacc[2][qh][1]),
                       fmaxf(sacc[2][qh][2], sacc[2][qh][3]));
      float a3 = fmaxf(fmaxf(sacc[3][qh][0], sacc[3][qh][1]),
                       fmaxf(sacc[3][qh][2], sacc[3][qh][3]));
      float tm = fmaxf(fmaxf(a0, a1), fmaxf(a2, a3));
      tm = fmaxf(tm, __shfl_xor(tm, 16));
      tm = fmaxf(tm, __shfl_xor(tm, 32));

      float pv[4][4];
      float ps = 0.f;
      if (__any(tm > 6.0f)) {
        const float dl = fmaxf(tm, 0.f);
        const float al = exp2f(-dl);
        mrun[qh] += dl;
        #pragma unroll
        for (int kt = 0; kt < 4; ++kt)
          #pragma unroll
          for (int rr = 0; rr < 4; ++rr) {
            const float pp = exp2f(sacc[kt][qh][rr] - dl);
            pv[kt][rr] = pp;
            ps += pp;
          }
        ps += __shfl_xor(ps, 16);
        ps += __shfl_xor(ps, 32);
        lrun[qh] = lrun[qh] * al + ps;
        #pragma unroll
        for (int dt = 0; dt < 4; ++dt)
          #pragma unroll
          for (int rr = 0; rr < 4; ++rr)
            o[dt][qh][rr] *= al;
      } else {
        #pragma unroll
        for (int kt = 0; kt < 4; ++kt)
          #pragma unroll
          for (int rr = 0; rr < 4; ++rr) {
            const float pp = exp2f(sacc[kt][qh][rr]);
            pv[kt][rr] = pp;
            ps += pp;
          }
        ps += __shfl_xor(ps, 16);
        ps += __shfl_xor(ps, 32);
        lrun[qh] += ps;
      }
      // pf[c][j] = P at key 32c + 16*(j>>2) + 4g + (j&3)
      #pragma unroll
      for (int c = 0; c < 2; ++c)
        #pragma unroll
        for (int j = 0; j < 8; ++j)
          pf[qh][c][j] = (__bf16)pv[2 * c + (j >> 2)][j & 3];
    }

    // --- PV: A = V (sigma-ordered cols from LDS), B = P (same order) ---
    __builtin_amdgcn_s_setprio(1);
    #pragma unroll
    for (int c = 0; c < 2; ++c)
      #pragma unroll
      for (int dt = 0; dt < 4; ++dt) {
        const bf16x8 vf = *(const bf16x8*)&v_sh[dt * 16 + r][c * 32 + g * 8];
        o[dt][0] = MFMA16(vf, pf[0][c], o[dt][0]);
        o[dt][1] = MFMA16(vf, pf[1][c], o[dt][1]);
      }
    __builtin_amdgcn_s_setprio(0);
  }

  // --- epilogue: normalize, write AO[b, s, h*64+d] (d = dt*16+4g+rr) ---
  #pragma unroll
  for (int qh = 0; qh < 2; ++qh) {
    const float inv = 1.0f / lrun[qh];
    const int ss = q0 + qh * 16 + r;
    #pragma unroll
    for (int dt = 0; dt < 4; ++dt) {
      bf16x4 ov;
      #pragma unroll
      for (int rr = 0; rr < 4; ++rr)
        ov[rr] = (__bf16)(o[dt][qh][rr] * inv);
      *(bf16x4*)&AO[((size_t)b * 2048 + ss) * 1024 + h * 64 + dt * 16 + 4 * g] = ov;
    }
  }
}

// ---------------------------------------------------------------------------
extern "C" void kernel_launch(void* const* d_in, const int* in_sizes, int n_in,
                              void* d_out, int out_size, void* d_ws, size_t ws_size,
                              hipStream_t stream) {
  (void)in_sizes; (void)n_in; (void)out_size; (void)ws_size;
  const float* x      = (const float*)d_in[0];
  const float* w_qkv  = (const float*)d_in[1];
  const float* b_qkv  = (const float*)d_in[2];
  const float* w_proj = (const float*)d_in[3];
  const float* b_proj = (const float*)d_in[4];
  float* out = (float*)d_out;

  char* ws = (char*)d_ws;
  const size_t E2 = (size_t)8192 * 1024 * 2;  // bytes per [8192][1024] bf16
  __bf16* Qb  = (__bf16*)(ws);
  __bf16* Kb  = (__bf16*)(ws + E2);
  __bf16* Vt  = (__bf16*)(ws + 2 * E2);
  __bf16* Xb  = (__bf16*)(ws + 3 * E2);
  __bf16* AO  = Xb;  // Xb dead after qkv_gemm_b; reuse for attention output
  __bf16* Wqt = (__bf16*)(ws + 4 * E2);
  __bf16* Wpt = (__bf16*)(ws + 4 * E2 + (size_t)3072 * 1024 * 2);

  conv_x<<<4096, 256, 0, stream>>>(x, Xb);
  conv_wt<<<dim3(48, 16), 256, 0, stream>>>(w_qkv, Wqt, 1024, 3072);
  conv_wt<<<dim3(16, 16), 256, 0, stream>>>(w_proj, Wpt, 1024, 1024);
  qkv_gemm_b<<<dim3(24, 64), 256, 0, stream>>>(Xb, Wqt, b_qkv, Qb, Kb, Vt);
  attn_kernel<<<1024, 256, 0, stream>>>(Qb, Kb, Vt, AO);
  proj_gemm_b<<<dim3(8, 64), 256, 0, stream>>>(AO, Wpt, b_proj, out);
}